// Round 9
// baseline (292.341 us; speedup 1.0000x reference)
//
#include <hip/hip_runtime.h>
#include <hip/hip_bf16.h>

#define B_    64
#define T_    256
#define K_    256
#define L_    51
#define LL_   2601
#define RS_   64      // row stride inside one tile
#define NG_   3328    // GEMM N: 52*64 (j rows 0..51; row 51 zero)
#define PST_  4096    // tile stride per (b,t): 64 rows * 64 elems
#define MT_   128
#define NT_   128

typedef __bf16 bf16x8 __attribute__((ext_vector_type(8)));
typedef float  f32x4  __attribute__((ext_vector_type(4)));
typedef unsigned int u32x4 __attribute__((ext_vector_type(4)));
typedef u32x4 __attribute__((may_alias)) u32x4_a;
typedef unsigned long long ull;
typedef ull __attribute__((may_alias)) ull_a;
typedef unsigned short ushort_a __attribute__((may_alias));

static __device__ __forceinline__ bf16x8 as_bf16x8(u32x4 u) {
    return __builtin_bit_cast(bf16x8, u);
}
static __device__ __forceinline__ unsigned short bf16bits(float x) {
    return __builtin_bit_cast(unsigned short, __float2bfloat16(x));
}
static __device__ __forceinline__ ull pack4(f32x4 a) {
    return (ull)bf16bits(a[0]) | ((ull)bf16bits(a[1]) << 16) |
           ((ull)bf16bits(a[2]) << 32) | ((ull)bf16bits(a[3]) << 48);
}
static __device__ __forceinline__ void gld_lds16(const void* g, void* l) {
    __builtin_amdgcn_global_load_lds(
        (const __attribute__((address_space(1))) unsigned int*)g,
        (__attribute__((address_space(3))) unsigned int*)l, 16, 0, 0);
}

#define DPP_STEP(v, OP, CTRL)                                                   \
    {                                                                           \
        int _x = __builtin_bit_cast(int, v);                                    \
        float _o = __builtin_bit_cast(                                          \
            float, __builtin_amdgcn_update_dpp(_x, _x, CTRL, 0xF, 0xF, true));  \
        v = OP(v, _o);                                                          \
    }
static __device__ __forceinline__ float addf(float a, float b) { return a + b; }

// ---------------------------------------------------------------------------
// prep_all: blk [0,64)   -> Wt rows n=j*64+i for i=blk (LDS transpose) + bias
//           blk [64,1088)-> x fp32 -> bf16
//           blk [1088,2112) -> zero P tile pad rows [NG_,PST_)
// ---------------------------------------------------------------------------
__global__ __launch_bounds__(256) void prep_all(
    const float* __restrict__ trans_W, const float* __restrict__ trans_b,
    const float* __restrict__ state_W, const float* __restrict__ state_b,
    const float* __restrict__ x,
    __hip_bfloat16* __restrict__ Wt, float* __restrict__ bias,
    __hip_bfloat16* __restrict__ xb, __hip_bfloat16* __restrict__ P, int Tc)
{
    __shared__ __align__(16) __hip_bfloat16 Wl[52 * 258];
    const int blk = blockIdx.x, tid = threadIdx.x;

    if (blk < 64) {
        const int i = blk;
        if (i < L_) {
            const int jp = tid & 63, kk = tid >> 6;
            if (jp < 52) {
                for (int k = kk; k < K_; k += 4) {
                    float v = 0.f;
                    if (jp < L_) v = trans_W[(size_t)k * LL_ + i * L_ + jp] +
                                     state_W[k * L_ + jp];
                    Wl[jp * 258 + k] = __float2bfloat16(v);
                }
            }
            __syncthreads();
            for (int idx = tid; idx < 52 * 32; idx += 256) {
                const int j = idx >> 5, c = idx & 31;
                const unsigned int* row = (const unsigned int*)&Wl[j * 258];
                u32x4 v;
                v[0] = row[c * 4 + 0]; v[1] = row[c * 4 + 1];
                v[2] = row[c * 4 + 2]; v[3] = row[c * 4 + 3];
                *(u32x4*)(Wt + (size_t)((j << 6) + i) * K_ + c * 8) = v;
            }
        } else {
            const u32x4 z = {};
            for (int idx = tid; idx < 52 * 32; idx += 256) {
                const int j = idx >> 5, c = idx & 31;
                *(u32x4*)(Wt + (size_t)((j << 6) + i) * K_ + c * 8) = z;
            }
        }
        if (tid < 52) {
            const int j = tid;
            bias[(j << 6) + i] =
                (i < L_ && j < L_) ? trans_b[i * L_ + j] + state_b[j] : 0.f;
        }
    } else if (blk < 64 + 1024) {
        const int n4 = B_ * T_ * K_ / 4;
        const float4* x4 = (const float4*)x;
        ushort4* xb4 = (ushort4*)xb;
        for (int idx = (blk - 64) * 256 + tid; idx < n4; idx += 1024 * 256) {
            float4 v = x4[idx];
            ushort4 o;
            o.x = bf16bits(v.x); o.y = bf16bits(v.y);
            o.z = bf16bits(v.z); o.w = bf16bits(v.w);
            xb4[idx] = o;
        }
    } else {
        const int per = (PST_ - NG_) / 8;          // 96 chunks per tile
        const int tot = B_ * Tc * per;
        u32x4* P16 = (u32x4*)P;
        const u32x4 z = {};
        for (int idx = (blk - 1088) * 256 + tid; idx < tot; idx += 1024 * 256) {
            const int m = idx / per;
            const int q = idx - m * per;
            P16[(size_t)m * (PST_ / 8) + (NG_ / 8) + q] = z;
        }
    }
}

// ---------------------------------------------------------------------------
// GEMM + exp epilogue. 4 K-phases of 64, 32 KB LDS, 5 blocks/CU.
// Grid (x=m-block, y=n-block): fixed m-block pins to one XCD -> xb L2-resident.
// Epilogue: result tile staged into As/Bs union (8B-rotated rows) ->
// fully coalesced 16B global stores.
// ---------------------------------------------------------------------------
__global__ __launch_bounds__(256, 5) void gemm_energy(
    const __hip_bfloat16* __restrict__ xb,   // [B*T][K]
    const __hip_bfloat16* __restrict__ Wt,   // [NG][K]
    const float* __restrict__ bias,          // [NG]
    const float* __restrict__ mask,          // [B][T]
    __hip_bfloat16* __restrict__ P,          // [B*Tc][PST]
    int t0, int Tc, int TcShift)
{
    __shared__ __align__(16) __hip_bfloat16 As[MT_ * 64];   // 16 KB
    __shared__ __align__(16) __hip_bfloat16 Bs[NT_ * 64];   // 16 KB

    const int tid  = threadIdx.x;
    const int lane = tid & 63;
    const int wv   = tid >> 6;
    const int quad = lane >> 4;
    const int l16  = lane & 15;
    const int m0 = blockIdx.x * MT_;
    const int n0 = blockIdx.y * NT_;
    const int mrow0 = (wv >> 1) * 64;
    const int ncol0 = (wv & 1) * 64;

    f32x4 acc[4][4] = {};   // [mf][nf]

    for (int kp = 0; kp < 4; ++kp) {
        if (kp) __syncthreads();             // safe LDS reuse
#pragma unroll
        for (int it = 0; it < 4; ++it) {
            const int s = it * 256 + tid;    // 16B-chunk slot (1024 per matrix)
            const int r = s >> 3;            // tile row 0..127
            const int c = (lane & 7) ^ (r & 7);  // swizzled source chunk
            const int ma = m0 + r;
            const int rg = (ma >> TcShift) * T_ + t0 + (ma & (Tc - 1));
            gld_lds16((const char*)xb + (size_t)rg * 512 + kp * 128 + c * 16,
                      (char*)As + it * 4096 + wv * 1024);
            gld_lds16((const char*)Wt + (size_t)(n0 + r) * 512 + kp * 128 + c * 16,
                      (char*)Bs + it * 4096 + wv * 1024);
        }
        asm volatile("s_waitcnt vmcnt(0)" ::: "memory");
        __syncthreads();

        const u32x4_a* Av = (const u32x4_a*)As;
        const u32x4_a* Bv = (const u32x4_a*)Bs;
#pragma unroll
        for (int kk = 0; kk < 2; ++kk) {
            bf16x8 af[4], bfr[4];
#pragma unroll
            for (int f = 0; f < 4; ++f) {
                const int ra = mrow0 + f * 16 + l16;
                af[f]  = as_bf16x8(Av[ra * 8 + ((kk * 4 + quad) ^ (ra & 7))]);
                const int rb = ncol0 + f * 16 + l16;
                bfr[f] = as_bf16x8(Bv[rb * 8 + ((kk * 4 + quad) ^ (rb & 7))]);
            }
#pragma unroll
            for (int mf = 0; mf < 4; ++mf)
#pragma unroll
                for (int nf = 0; nf < 4; ++nf)
                    acc[mf][nf] = __builtin_amdgcn_mfma_f32_16x16x32_bf16(
                        af[mf], bfr[nf], acc[mf][nf], 0, 0, 0);
        }
    }
    __syncthreads();   // done with As/Bs as staging; reuse as epilogue tile

    // Epilogue tile E: 128 rows x 256 B, row ml physically rotated by 8*(ml&31)
    char* E = (char*)As;
    const int jcol = (n0 + ncol0) >> 6;     // wave-uniform tile row j
    const bool jok = jcol < L_;
    float bv[4]; bool ok[4]; int ii[4];
#pragma unroll
    for (int nf = 0; nf < 4; ++nf) {
        const int n = n0 + ncol0 + nf * 16 + l16;
        ii[nf]   = nf * 16 + l16;           // i within tile
        ok[nf]   = jok && (ii[nf] < L_);
        bv[nf]   = bias[n];
    }
#pragma unroll
    for (int mf = 0; mf < 4; ++mf) {
#pragma unroll
        for (int r = 0; r < 4; ++r) {
            const int ml = mrow0 + mf * 16 + quad * 4 + r;
            const int m  = m0 + ml;
            const int bb = m >> TcShift;
            const int tl = m & (Tc - 1);
            const int t  = t0 + tl;
            const float mval = mask[bb * T_ + t];
            const bool idm = (mval == 0.f) && (t != 0);
            char* erow = E + ml * 256;
            const int rot = (ml * 8) & 255;
#pragma unroll
            for (int nf = 0; nf < 4; ++nf) {
                float v;
                if (idm) v = (ok[nf] && ii[nf] == jcol) ? 1.f : 0.f;
                else     v = ok[nf] ? __expf((acc[mf][nf][r] + bv[nf]) * mval) : 0.f;
                const int nloc = ncol0 + nf * 16 + l16;
                *(ushort_a*)(erow + ((nloc * 2 + rot) & 255)) = bf16bits(v);
            }
        }
    }
    __syncthreads();

    // Coalesced store: 16 lanes cover one row's 256 B contiguous
#pragma unroll
    for (int it2 = 0; it2 < 8; ++it2) {
        const int idx = it2 * 256 + tid;
        const int ml = idx >> 4, c = idx & 15;
        const char* erow = E + ml * 256;
        const int rot = (ml * 8) & 255;
        const ull lo = *(const ull_a*)(erow + ((c * 16 + rot) & 255));
        const ull hi = *(const ull_a*)(erow + ((c * 16 + 8 + rot) & 255));
        u32x4 v;
        v[0] = (unsigned int)lo; v[1] = (unsigned int)(lo >> 32);
        v[2] = (unsigned int)hi; v[3] = (unsigned int)(hi >> 32);
        *(u32x4*)(P + (size_t)(m0 + ml) * PST_ + n0 + c * 8) = v;
    }
}

// ---------------------------------------------------------------------------
// prod_quad: Q = T4·T3·T2·T1, all-MFMA pair tree. 48 KB LDS (3 blocks/CU):
// trans bufs use 16B-rotation swizzle (stride 64, no pad); W2t/W4b overlay
// the consumed Sm[0]/Sm[2] staging tiles.
// ---------------------------------------------------------------------------
__global__ __launch_bounds__(256, 3) void prod_quad(
    const __hip_bfloat16* __restrict__ P,   // [B*Tc][PST]
    __hip_bfloat16* __restrict__ Q,         // [B*(Tc/4)][PST]
    int Tc)
{
    __shared__ u32x4 Sm[4][512];                            // 32 KB
    __shared__ __align__(16) unsigned short Tb[2][64 * 64]; // 16 KB

    unsigned short* W2t = (unsigned short*)&Sm[0][0];       // reused after phase A
    unsigned short* W4b = (unsigned short*)&Sm[2][0];

    const int tid  = threadIdx.x;
    const int wv   = tid >> 6;
    const int lane = tid & 63;
    const int quad = lane >> 4;
    const int l16  = lane & 15;
    const int bq = blockIdx.x;
    const int Tq = Tc >> 2;
    const int b  = bq / Tq;
    const int tq = bq - b * Tq;
    const __hip_bfloat16* tile0 = P + (size_t)(b * Tc + tq * 4) * PST_;

#pragma unroll
    for (int q = 0; q < 8; ++q) {
        const int idx  = q * 4 + wv;
        const int tile = idx >> 3;
        const int part = idx & 7;
        const int slot = part * 64 + lane;
        const int r    = slot >> 3;
        const int csrc = (slot & 7) ^ (r & 7);
        gld_lds16((const char*)(tile0 + (size_t)tile * PST_) + (r * 8 + csrc) * 16,
                  (char*)&Sm[tile][part * 64]);
    }

    u32x4 idf[2];
    {
        const int e = l16 & 7;
        const unsigned int bits = (e & 1) ? 0x3F800000u : 0x3F80u;
#pragma unroll
        for (int par = 0; par < 2; ++par) {
            u32x4 v = {};
            if (quad == (l16 >> 3) + par * 2) v[e >> 1] = bits;
            idf[par] = v;
        }
    }

    // rotated transpose-buffer accessors (row = 128 B, rot = 16*(row&7))
    auto twr = [&](unsigned short* buf, int rb, int colb, ull v) {
        *(ull_a*)((char*)buf + rb * 128 + ((colb + 16 * (rb & 7)) & 127)) = v;
    };
    auto trd = [&](const unsigned short* buf, int r, int colb) -> u32x4 {
        return *(const u32x4_a*)((char*)buf + r * 128 + ((colb + 16 * (r & 7)) & 127));
    };
    const int wcol = wv * 32 + quad * 8;    // transposed-write byte col

    const int ra = wv * 16 + l16;
    const f32x4 z = {};
    asm volatile("s_waitcnt vmcnt(0)" ::: "memory");
    __syncthreads();

    // Phase A: Tb[0] = T1^T rows, Tb[1] = T3^T rows (identity MFMA)
#pragma unroll
    for (int tt = 0; tt < 2; ++tt) {
        const u32x4* S = Sm[tt * 2];
        bf16x8 a0 = as_bf16x8(S[ra * 8 + (quad ^ (ra & 7))]);
        bf16x8 a1 = as_bf16x8(S[ra * 8 + ((4 + quad) ^ (ra & 7))]);
#pragma unroll
        for (int nf = 0; nf < 4; ++nf) {
            f32x4 d = __builtin_amdgcn_mfma_f32_16x16x32_bf16(
                (nf >> 1) ? a1 : a0, as_bf16x8(idf[nf & 1]), z, 0, 0, 0);
            twr(Tb[tt], nf * 16 + l16, wcol, pack4(d));
        }
    }
    __syncthreads();

    // Phase B: W2 = T2·T1 (store W2^T rows -> Sm[0]); W4^T = T3^T·T4^T (-> Sm[2])
    {
        bf16x8 a2[2], a3[2];
#pragma unroll
        for (int ks = 0; ks < 2; ++ks) {
            a2[ks] = as_bf16x8(Sm[1][ra * 8 + ((ks * 4 + quad) ^ (ra & 7))]);
            a3[ks] = as_bf16x8(trd(Tb[1], ra, ks * 64 + quad * 16));
        }
        ull w2v[4], w4v[4];
#pragma unroll
        for (int nf = 0; nf < 4; ++nf) {
            const int rb = nf * 16 + l16;
            f32x4 u = z, v = z;
#pragma unroll
            for (int ks = 0; ks < 2; ++ks) {
                bf16x8 bU = as_bf16x8(trd(Tb[0], rb, ks * 64 + quad * 16));
                bf16x8 bV = as_bf16x8(Sm[3][rb * 8 + ((ks * 4 + quad) ^ (rb & 7))]);
                u = __builtin_amdgcn_mfma_f32_16x16x32_bf16(a2[ks], bU, u, 0, 0, 0);
                v = __builtin_amdgcn_mfma_f32_16x16x32_bf16(a3[ks], bV, v, 0, 0, 0);
            }
            w2v[nf] = pack4(u);
            w4v[nf] = pack4(v);
        }
        __syncthreads();   // Sm[0]/Sm[2] reads (phase A) done everywhere
#pragma unroll
        for (int nf = 0; nf < 4; ++nf) {
            twr(W2t, nf * 16 + l16, wcol, w2v[nf]);
            twr(W4b, nf * 16 + l16, wcol, w4v[nf]);
        }
    }
    __syncthreads();

    // Phase C: M rows -> Tb[0]
    {
        bf16x8 aw[2];
#pragma unroll
        for (int ks = 0; ks < 2; ++ks)
            aw[ks] = as_bf16x8(trd(W2t, ra, ks * 64 + quad * 16));
        ull mv[4];
#pragma unroll
        for (int nf = 0; nf < 4; ++nf) {
            const int rb = nf * 16 + l16;
            f32x4 d = z;
#pragma unroll
            for (int ks = 0; ks < 2; ++ks) {
                bf16x8 bw = as_bf16x8(trd(W4b, rb, ks * 64 + quad * 16));
                d = __builtin_amdgcn_mfma_f32_16x16x32_bf16(aw[ks], bw, d, 0, 0, 0);
            }
            mv[nf] = pack4(d);
        }
        __syncthreads();   // Tb[0] reads (phase B) done
#pragma unroll
        for (int nf = 0; nf < 4; ++nf)
            twr(Tb[0], nf * 16 + l16, wcol, mv[nf]);
    }
    __syncthreads();

    u32x4* qout = (u32x4*)(Q + (size_t)bq * PST_);
#pragma unroll
    for (int c = tid; c < 512; c += 256) {
        const int row = c >> 3;
        const int pos = c & 7;
        qout[row * 8 + pos] = trd(Tb[0], row, pos * 16);
    }
}

// ---------------------------------------------------------------------------
// scan_q: wave 0 = serial scan over quad-products (64 steps);
//         wave 1 = target-path gather (concurrent, off the critical path).
// ---------------------------------------------------------------------------
__global__ __launch_bounds__(128, 1) void scan_q(
    const __hip_bfloat16* __restrict__ Q,    // [B*Tq][PST]
    const __hip_bfloat16* __restrict__ P,    // [B*Tc][PST]
    const int* __restrict__ target, const float* __restrict__ mask,
    float* __restrict__ p_ws, float* __restrict__ ls_ws,
    float* __restrict__ tgt_ws, float* __restrict__ out,
    int t0q, int Tq, int Tqtot)
{
    __shared__ __align__(16) unsigned short p_arr[64];
    __shared__ float tgt_sh;

    const int b    = blockIdx.x;
    const int tid  = threadIdx.x;
    const int wv   = tid >> 6;
    const int lane = tid & 63;
    const int quad = lane >> 4;
    const int l16  = lane & 15;
    const int t0 = t0q << 2, Tc = Tq << 2;

    float pv[4] = {0.f, 0.f, 0.f, 0.f};
    float logscale = 0.f;

    if (wv == 0) {
        if (t0q == 0) {
            p_arr[lane] = (lane == L_ - 1) ? (unsigned short)0x3F80 : (unsigned short)0;
        } else {
#pragma unroll
            for (int f = 0; f < 4; ++f) pv[f] = p_ws[b * 64 + f * 16 + l16];
            logscale = ls_ws[b];
            p_arr[quad * 16 + l16] = bf16bits(pv[quad]);
        }
        asm volatile("s_waitcnt lgkmcnt(0)" ::: "memory");

        int off[8];
#pragma unroll
        for (int f = 0; f < 4; ++f)
#pragma unroll
            for (int ks = 0; ks < 2; ++ks)
                off[f * 2 + ks] = (f * 16 + l16) * 8 + ks * 4 + quad;

        const u32x4* gp = (const u32x4*)Q + (size_t)b * Tq * (PST_ / 8);
        const u32x4_a* pa = (const u32x4_a*)p_arr;

        u32x4 s0[8], s1[8], s2[8], s3[8];
        auto fetch = [&](u32x4 (&st)[8], int tl) {
            const u32x4* g = gp + (size_t)tl * (PST_ / 8);
#pragma unroll
            for (int q = 0; q < 8; ++q) st[q] = g[off[q]];
        };
        fetch(s0, 0);
        if (1 < Tq) fetch(s1, 1);
        if (2 < Tq) fetch(s2, 2);
        if (3 < Tq) fetch(s3, 3);

        auto step = [&](u32x4 (&st)[8], int tl) {
            bf16x8 a0 = as_bf16x8(pa[quad]);
            bf16x8 a1 = as_bf16x8(pa[4 + quad]);
            const f32x4 z = {};
            f32x4 ae[4], ao[4];
#pragma unroll
            for (int f = 0; f < 4; ++f) {
                ae[f] = __builtin_amdgcn_mfma_f32_16x16x32_bf16(a0, as_bf16x8(st[f * 2 + 0]), z, 0, 0, 0);
                ao[f] = __builtin_amdgcn_mfma_f32_16x16x32_bf16(a1, as_bf16x8(st[f * 2 + 1]), z, 0, 0, 0);
            }
#pragma unroll
            for (int f = 0; f < 4; ++f) pv[f] = ae[f][0] + ao[f][0];

            if (((tl & 1) == 1) || (tl == Tq - 1)) {
                float mx = fmaxf(fmaxf(pv[0], pv[1]), fmaxf(pv[2], pv[3]));
                DPP_STEP(mx, fmaxf, 0xB1);
                DPP_STEP(mx, fmaxf, 0x4E);
                DPP_STEP(mx, fmaxf, 0x124);
                DPP_STEP(mx, fmaxf, 0x128);
                const float inv = 1.f / mx;
                logscale += __logf(mx);
#pragma unroll
                for (int f = 0; f < 4; ++f) pv[f] *= inv;
            }
            p_arr[quad * 16 + l16] = bf16bits(pv[quad]);
            asm volatile("s_waitcnt lgkmcnt(0)" ::: "memory");
        };

        for (int tl = 0; tl < Tq; tl += 4) {
            step(s0, tl);
            if (tl + 4 < Tq) fetch(s0, tl + 4);
            if (tl + 1 < Tq) { step(s1, tl + 1); if (tl + 5 < Tq) fetch(s1, tl + 5); }
            if (tl + 2 < Tq) { step(s2, tl + 2); if (tl + 6 < Tq) fetch(s2, tl + 6); }
            if (tl + 3 < Tq) { step(s3, tl + 3); if (tl + 7 < Tq) fetch(s3, tl + 7); }
        }
    } else {
        // target-path gather
        float s = 0.f;
        for (int tl = lane; tl < Tc; tl += 64) {
            const int t = t0 + tl;
            const int j = target[b * T_ + t];
            const int i = (t == 0) ? (L_ - 1) : target[b * T_ + t - 1];
            const float m = (t == 0) ? 1.f : mask[b * T_ + t];
            if (m != 0.f) {
                const float pval =
                    __bfloat162float(P[(size_t)(b * Tc + tl) * PST_ + j * RS_ + i]);
                s += __logf(pval);
            }
        }
#pragma unroll
        for (int d = 1; d < 64; d <<= 1) s += __shfl_xor(s, d);
        if (lane == 0) {
            const float tot = (t0 == 0) ? s : tgt_ws[b] + s;
            tgt_ws[b] = tot;
            tgt_sh = tot;
        }
    }
    __syncthreads();

    if (wv == 0) {
        if (t0q + Tq == Tqtot) {
            float s = pv[0] + pv[1] + pv[2] + pv[3];
            DPP_STEP(s, addf, 0xB1);
            DPP_STEP(s, addf, 0x4E);
            DPP_STEP(s, addf, 0x124);
            DPP_STEP(s, addf, 0x128);
            if (lane == 0) out[b] = logscale + __logf(s) - tgt_sh;
        } else {
            if (quad == 0) {
#pragma unroll
                for (int f = 0; f < 4; ++f) p_ws[b * 64 + f * 16 + l16] = pv[f];
            }
            if (lane == 0) ls_ws[b] = logscale;
        }
    }
}

// ---------------------------------------------------------------------------
extern "C" void kernel_launch(void* const* d_in, const int* in_sizes, int n_in,
                              void* d_out, int out_size, void* d_ws, size_t ws_size,
                              hipStream_t stream)
{
    (void)in_sizes; (void)n_in; (void)out_size;
    const float* x       = (const float*)d_in[0];
    const float* mask    = (const float*)d_in[1];
    const int*   target  = (const int*)d_in[2];
    const float* state_W = (const float*)d_in[3];
    const float* state_b = (const float*)d_in[4];
    const float* trans_W = (const float*)d_in[5];
    const float* trans_b = (const float*)d_in[6];
    float* out = (float*)d_out;

    char* ws = (char*)d_ws;
    size_t off = 0;
    auto alloc = [&](size_t bytes) -> void* {
        void* p = ws + off;
        off = (off + bytes + 255) & ~(size_t)255;
        return p;
    };

    __hip_bfloat16* Wt   = (__hip_bfloat16*)alloc((size_t)NG_ * K_ * 2);
    float*          bias = (float*)alloc((size_t)NG_ * 4);
    __hip_bfloat16* xb   = (__hip_bfloat16*)alloc((size_t)B_ * T_ * K_ * 2);
    float*          p_ws = (float*)alloc((size_t)B_ * 64 * 4);
    float*          ls   = (float*)alloc((size_t)B_ * 4);
    float*          tgte = (float*)alloc((size_t)B_ * 4);
    const size_t fixed = off;

    int Tc = 256;
    while (Tc > 4 && fixed + (size_t)Tc * B_ * PST_ * 2 * 5 / 4 + 512 > ws_size) Tc >>= 1;
    __hip_bfloat16* P = (__hip_bfloat16*)alloc((size_t)Tc * B_ * PST_ * 2);
    __hip_bfloat16* Q = (__hip_bfloat16*)alloc((size_t)(Tc / 4) * B_ * PST_ * 2);
    int TcShift = 0;
    while ((1 << TcShift) < Tc) ++TcShift;

    prep_all<<<dim3(2112), 256, 0, stream>>>(
        trans_W, trans_b, state_W, state_b, x, Wt, bias, xb, P, Tc);

    for (int t0 = 0; t0 < T_; t0 += Tc) {
        gemm_energy<<<dim3((B_ * Tc) / MT_, NG_ / NT_), 256, 0, stream>>>(
            xb, Wt, bias, mask, P, t0, Tc, TcShift);
        prod_quad<<<dim3(B_ * (Tc / 4)), 256, 0, stream>>>(P, Q, Tc);
        scan_q<<<dim3(B_), 128, 0, stream>>>(Q, P, target, mask, p_ws, ls, tgte, out,
                                             t0 / 4, Tc / 4, T_ / 4);
    }
}

// Round 10
// 206.644 us; speedup vs baseline: 1.4147x; 1.4147x over previous
//
#include <hip/hip_runtime.h>
#include <hip/hip_bf16.h>

#define B_    64
#define T_    256
#define K_    256
#define L_    51
#define LL_   2601
#define RS_   64      // row stride inside one tile
#define NG_   3328    // GEMM N: 52*64 (j rows 0..51; row 51 zero)
#define PST_  4096    // tile stride per (b,t): 64 rows * 64 elems
#define MT_   128
#define NT_   128

typedef __bf16 bf16x8 __attribute__((ext_vector_type(8)));
typedef float  f32x4  __attribute__((ext_vector_type(4)));
typedef unsigned int u32x4 __attribute__((ext_vector_type(4)));
typedef u32x4 __attribute__((may_alias)) u32x4_a;
typedef unsigned long long ull;
typedef ull __attribute__((may_alias)) ull_a;
typedef unsigned short ushort_a __attribute__((may_alias));

static __device__ __forceinline__ bf16x8 as_bf16x8(u32x4 u) {
    return __builtin_bit_cast(bf16x8, u);
}
static __device__ __forceinline__ unsigned short bf16bits(float x) {
    return __builtin_bit_cast(unsigned short, __float2bfloat16(x));
}
static __device__ __forceinline__ ull pack4(f32x4 a) {
    return (ull)bf16bits(a[0]) | ((ull)bf16bits(a[1]) << 16) |
           ((ull)bf16bits(a[2]) << 32) | ((ull)bf16bits(a[3]) << 48);
}
static __device__ __forceinline__ void gld_lds16(const void* g, void* l) {
    __builtin_amdgcn_global_load_lds(
        (const __attribute__((address_space(1))) unsigned int*)g,
        (__attribute__((address_space(3))) unsigned int*)l, 16, 0, 0);
}

#define DPP_STEP(v, OP, CTRL)                                                   \
    {                                                                           \
        int _x = __builtin_bit_cast(int, v);                                    \
        float _o = __builtin_bit_cast(                                          \
            float, __builtin_amdgcn_update_dpp(_x, _x, CTRL, 0xF, 0xF, true));  \
        v = OP(v, _o);                                                          \
    }
static __device__ __forceinline__ float addf(float a, float b) { return a + b; }

// ---------------------------------------------------------------------------
// prep_all: blk [0,64)   -> Wt rows n=j*64+i for i=blk (LDS transpose) + bias
//           blk [64,1088)-> x fp32 -> bf16
//           blk [1088,2112) -> zero P tile pad rows [NG_,PST_)
// ---------------------------------------------------------------------------
__global__ __launch_bounds__(256) void prep_all(
    const float* __restrict__ trans_W, const float* __restrict__ trans_b,
    const float* __restrict__ state_W, const float* __restrict__ state_b,
    const float* __restrict__ x,
    __hip_bfloat16* __restrict__ Wt, float* __restrict__ bias,
    __hip_bfloat16* __restrict__ xb, __hip_bfloat16* __restrict__ P, int Tc)
{
    __shared__ __align__(16) __hip_bfloat16 Wl[52 * 258];
    const int blk = blockIdx.x, tid = threadIdx.x;

    if (blk < 64) {
        const int i = blk;
        if (i < L_) {
            const int jp = tid & 63, kk = tid >> 6;
            if (jp < 52) {
                for (int k = kk; k < K_; k += 4) {
                    float v = 0.f;
                    if (jp < L_) v = trans_W[(size_t)k * LL_ + i * L_ + jp] +
                                     state_W[k * L_ + jp];
                    Wl[jp * 258 + k] = __float2bfloat16(v);
                }
            }
            __syncthreads();
            for (int idx = tid; idx < 52 * 32; idx += 256) {
                const int j = idx >> 5, c = idx & 31;
                const unsigned int* row = (const unsigned int*)&Wl[j * 258];
                u32x4 v;
                v[0] = row[c * 4 + 0]; v[1] = row[c * 4 + 1];
                v[2] = row[c * 4 + 2]; v[3] = row[c * 4 + 3];
                *(u32x4*)(Wt + (size_t)((j << 6) + i) * K_ + c * 8) = v;
            }
        } else {
            const u32x4 z = {};
            for (int idx = tid; idx < 52 * 32; idx += 256) {
                const int j = idx >> 5, c = idx & 31;
                *(u32x4*)(Wt + (size_t)((j << 6) + i) * K_ + c * 8) = z;
            }
        }
        if (tid < 52) {
            const int j = tid;
            bias[(j << 6) + i] =
                (i < L_ && j < L_) ? trans_b[i * L_ + j] + state_b[j] : 0.f;
        }
    } else if (blk < 64 + 1024) {
        const int n4 = B_ * T_ * K_ / 4;
        const float4* x4 = (const float4*)x;
        ushort4* xb4 = (ushort4*)xb;
        for (int idx = (blk - 64) * 256 + tid; idx < n4; idx += 1024 * 256) {
            float4 v = x4[idx];
            ushort4 o;
            o.x = bf16bits(v.x); o.y = bf16bits(v.y);
            o.z = bf16bits(v.z); o.w = bf16bits(v.w);
            xb4[idx] = o;
        }
    } else {
        const int per = (PST_ - NG_) / 8;          // 96 chunks per tile
        const int tot = B_ * Tc * per;
        u32x4* P16 = (u32x4*)P;
        const u32x4 z = {};
        for (int idx = (blk - 1088) * 256 + tid; idx < tot; idx += 1024 * 256) {
            const int m = idx / per;
            const int q = idx - m * per;
            P16[(size_t)m * (PST_ / 8) + (NG_ / 8) + q] = z;
        }
    }
}

// ---------------------------------------------------------------------------
// GEMM + exp epilogue. 4 K-phases of 64, 32 KB LDS -> 5 blocks/CU by LDS.
// NO min-waves launch bound (r9's ",5" forced VGPR=48 < 64 accum regs ->
// scratch spill, 3x phantom HBM traffic). Grid (x=n, y=m) as in r8.
// Epilogue staged through the As/Bs union -> 8x16B coalesced stores/thread.
// ---------------------------------------------------------------------------
__global__ __launch_bounds__(256) void gemm_energy(
    const __hip_bfloat16* __restrict__ xb,   // [B*T][K]
    const __hip_bfloat16* __restrict__ Wt,   // [NG][K]
    const float* __restrict__ bias,          // [NG]
    const float* __restrict__ mask,          // [B][T]
    __hip_bfloat16* __restrict__ P,          // [B*Tc][PST]
    int t0, int Tc, int TcShift)
{
    __shared__ __align__(16) __hip_bfloat16 As[MT_ * 64];   // 16 KB
    __shared__ __align__(16) __hip_bfloat16 Bs[NT_ * 64];   // 16 KB

    const int tid  = threadIdx.x;
    const int lane = tid & 63;
    const int wv   = tid >> 6;
    const int quad = lane >> 4;
    const int l16  = lane & 15;
    const int m0 = blockIdx.y * MT_;
    const int n0 = blockIdx.x * NT_;
    const int mrow0 = (wv >> 1) * 64;
    const int ncol0 = (wv & 1) * 64;

    f32x4 acc[4][4] = {};   // [mf][nf]

    for (int kp = 0; kp < 4; ++kp) {
        if (kp) __syncthreads();             // safe LDS reuse
#pragma unroll
        for (int it = 0; it < 4; ++it) {
            const int s = it * 256 + tid;    // 16B-chunk slot (1024 per matrix)
            const int r = s >> 3;            // tile row 0..127
            const int c = (lane & 7) ^ (r & 7);  // swizzled source chunk
            const int ma = m0 + r;
            const int rg = (ma >> TcShift) * T_ + t0 + (ma & (Tc - 1));
            gld_lds16((const char*)xb + (size_t)rg * 512 + kp * 128 + c * 16,
                      (char*)As + it * 4096 + wv * 1024);
            gld_lds16((const char*)Wt + (size_t)(n0 + r) * 512 + kp * 128 + c * 16,
                      (char*)Bs + it * 4096 + wv * 1024);
        }
        asm volatile("s_waitcnt vmcnt(0)" ::: "memory");
        __syncthreads();

        const u32x4_a* Av = (const u32x4_a*)As;
        const u32x4_a* Bv = (const u32x4_a*)Bs;
#pragma unroll
        for (int kk = 0; kk < 2; ++kk) {
            bf16x8 af[4], bfr[4];
#pragma unroll
            for (int f = 0; f < 4; ++f) {
                const int ra = mrow0 + f * 16 + l16;
                af[f]  = as_bf16x8(Av[ra * 8 + ((kk * 4 + quad) ^ (ra & 7))]);
                const int rb = ncol0 + f * 16 + l16;
                bfr[f] = as_bf16x8(Bv[rb * 8 + ((kk * 4 + quad) ^ (rb & 7))]);
            }
#pragma unroll
            for (int mf = 0; mf < 4; ++mf)
#pragma unroll
                for (int nf = 0; nf < 4; ++nf)
                    acc[mf][nf] = __builtin_amdgcn_mfma_f32_16x16x32_bf16(
                        af[mf], bfr[nf], acc[mf][nf], 0, 0, 0);
        }
    }
    __syncthreads();   // done with As/Bs as staging; reuse as epilogue tile

    // Epilogue tile E: 128 rows x 256 B, row ml physically rotated by 8*ml
    char* E = (char*)As;
    const int jcol = (n0 + ncol0) >> 6;     // wave-uniform tile row j
    const bool jok = jcol < L_;
    float bv[4]; bool ok[4]; int ii[4];
#pragma unroll
    for (int nf = 0; nf < 4; ++nf) {
        const int n = n0 + ncol0 + nf * 16 + l16;
        ii[nf]   = nf * 16 + l16;           // i within tile
        ok[nf]   = jok && (ii[nf] < L_);
        bv[nf]   = bias[n];
    }
#pragma unroll
    for (int mf = 0; mf < 4; ++mf) {
#pragma unroll
        for (int r = 0; r < 4; ++r) {
            const int ml = mrow0 + mf * 16 + quad * 4 + r;
            const int m  = m0 + ml;
            const int bb = m >> TcShift;
            const int tl = m & (Tc - 1);
            const int t  = t0 + tl;
            const float mval = mask[bb * T_ + t];
            const bool idm = (mval == 0.f) && (t != 0);
            char* erow = E + ml * 256;
            const int rot = (ml * 8) & 255;
#pragma unroll
            for (int nf = 0; nf < 4; ++nf) {
                float v;
                if (idm) v = (ok[nf] && ii[nf] == jcol) ? 1.f : 0.f;
                else     v = ok[nf] ? __expf((acc[mf][nf][r] + bv[nf]) * mval) : 0.f;
                const int nloc = ncol0 + nf * 16 + l16;
                *(ushort_a*)(erow + ((nloc * 2 + rot) & 255)) = bf16bits(v);
            }
        }
    }
    __syncthreads();

    // Coalesced store: 16 lanes cover one row's 256 B contiguous
#pragma unroll
    for (int it2 = 0; it2 < 8; ++it2) {
        const int idx = it2 * 256 + tid;
        const int ml = idx >> 4, c = idx & 15;
        const char* erow = E + ml * 256;
        const int rot = (ml * 8) & 255;
        const ull lo = *(const ull_a*)(erow + ((c * 16 + rot) & 255));
        const ull hi = *(const ull_a*)(erow + ((c * 16 + 8 + rot) & 255));
        u32x4 v;
        v[0] = (unsigned int)lo; v[1] = (unsigned int)(lo >> 32);
        v[2] = (unsigned int)hi; v[3] = (unsigned int)(hi >> 32);
        *(u32x4*)(P + (size_t)(m0 + ml) * PST_ + n0 + c * 8) = v;
    }
}

// ---------------------------------------------------------------------------
// prod_quad: Q = T4·T3·T2·T1, all-MFMA pair tree. 48 KB LDS (3 blocks/CU):
// trans bufs use 16B-rotation swizzle (stride 64, no pad); W2t/W4b overlay
// the consumed Sm[0]/Sm[2] staging tiles.
// ---------------------------------------------------------------------------
__global__ __launch_bounds__(256) void prod_quad(
    const __hip_bfloat16* __restrict__ P,   // [B*Tc][PST]
    __hip_bfloat16* __restrict__ Q,         // [B*(Tc/4)][PST]
    int Tc)
{
    __shared__ u32x4 Sm[4][512];                            // 32 KB
    __shared__ __align__(16) unsigned short Tb[2][64 * 64]; // 16 KB

    unsigned short* W2t = (unsigned short*)&Sm[0][0];       // reused after phase A
    unsigned short* W4b = (unsigned short*)&Sm[2][0];

    const int tid  = threadIdx.x;
    const int wv   = tid >> 6;
    const int lane = tid & 63;
    const int quad = lane >> 4;
    const int l16  = lane & 15;
    const int bq = blockIdx.x;
    const int Tq = Tc >> 2;
    const int b  = bq / Tq;
    const int tq = bq - b * Tq;
    const __hip_bfloat16* tile0 = P + (size_t)(b * Tc + tq * 4) * PST_;

#pragma unroll
    for (int q = 0; q < 8; ++q) {
        const int idx  = q * 4 + wv;
        const int tile = idx >> 3;
        const int part = idx & 7;
        const int slot = part * 64 + lane;
        const int r    = slot >> 3;
        const int csrc = (slot & 7) ^ (r & 7);
        gld_lds16((const char*)(tile0 + (size_t)tile * PST_) + (r * 8 + csrc) * 16,
                  (char*)&Sm[tile][part * 64]);
    }

    u32x4 idf[2];
    {
        const int e = l16 & 7;
        const unsigned int bits = (e & 1) ? 0x3F800000u : 0x3F80u;
#pragma unroll
        for (int par = 0; par < 2; ++par) {
            u32x4 v = {};
            if (quad == (l16 >> 3) + par * 2) v[e >> 1] = bits;
            idf[par] = v;
        }
    }

    // rotated transpose-buffer accessors (row = 128 B, rot = 16*(row&7))
    auto twr = [&](unsigned short* buf, int rb, int colb, ull v) {
        *(ull_a*)((char*)buf + rb * 128 + ((colb + 16 * (rb & 7)) & 127)) = v;
    };
    auto trd = [&](const unsigned short* buf, int r, int colb) -> u32x4 {
        return *(const u32x4_a*)((char*)buf + r * 128 + ((colb + 16 * (r & 7)) & 127));
    };
    const int wcol = wv * 32 + quad * 8;    // transposed-write byte col

    const int ra = wv * 16 + l16;
    const f32x4 z = {};
    asm volatile("s_waitcnt vmcnt(0)" ::: "memory");
    __syncthreads();

    // Phase A: Tb[0] = T1^T rows, Tb[1] = T3^T rows (identity MFMA)
#pragma unroll
    for (int tt = 0; tt < 2; ++tt) {
        const u32x4* S = Sm[tt * 2];
        bf16x8 a0 = as_bf16x8(S[ra * 8 + (quad ^ (ra & 7))]);
        bf16x8 a1 = as_bf16x8(S[ra * 8 + ((4 + quad) ^ (ra & 7))]);
#pragma unroll
        for (int nf = 0; nf < 4; ++nf) {
            f32x4 d = __builtin_amdgcn_mfma_f32_16x16x32_bf16(
                (nf >> 1) ? a1 : a0, as_bf16x8(idf[nf & 1]), z, 0, 0, 0);
            twr(Tb[tt], nf * 16 + l16, wcol, pack4(d));
        }
    }
    __syncthreads();

    // Phase B: W2 = T2·T1 (store W2^T rows -> Sm[0]); W4^T = T3^T·T4^T (-> Sm[2])
    {
        bf16x8 a2[2], a3[2];
#pragma unroll
        for (int ks = 0; ks < 2; ++ks) {
            a2[ks] = as_bf16x8(Sm[1][ra * 8 + ((ks * 4 + quad) ^ (ra & 7))]);
            a3[ks] = as_bf16x8(trd(Tb[1], ra, ks * 64 + quad * 16));
        }
        ull w2v[4], w4v[4];
#pragma unroll
        for (int nf = 0; nf < 4; ++nf) {
            const int rb = nf * 16 + l16;
            f32x4 u = z, v = z;
#pragma unroll
            for (int ks = 0; ks < 2; ++ks) {
                bf16x8 bU = as_bf16x8(trd(Tb[0], rb, ks * 64 + quad * 16));
                bf16x8 bV = as_bf16x8(Sm[3][rb * 8 + ((ks * 4 + quad) ^ (rb & 7))]);
                u = __builtin_amdgcn_mfma_f32_16x16x32_bf16(a2[ks], bU, u, 0, 0, 0);
                v = __builtin_amdgcn_mfma_f32_16x16x32_bf16(a3[ks], bV, v, 0, 0, 0);
            }
            w2v[nf] = pack4(u);
            w4v[nf] = pack4(v);
        }
        __syncthreads();   // Sm[0]/Sm[2] reads (phase A) done everywhere
#pragma unroll
        for (int nf = 0; nf < 4; ++nf) {
            twr(W2t, nf * 16 + l16, wcol, w2v[nf]);
            twr(W4b, nf * 16 + l16, wcol, w4v[nf]);
        }
    }
    __syncthreads();

    // Phase C: M rows -> Tb[0]
    {
        bf16x8 aw[2];
#pragma unroll
        for (int ks = 0; ks < 2; ++ks)
            aw[ks] = as_bf16x8(trd(W2t, ra, ks * 64 + quad * 16));
        ull mv[4];
#pragma unroll
        for (int nf = 0; nf < 4; ++nf) {
            const int rb = nf * 16 + l16;
            f32x4 d = z;
#pragma unroll
            for (int ks = 0; ks < 2; ++ks) {
                bf16x8 bw = as_bf16x8(trd(W4b, rb, ks * 64 + quad * 16));
                d = __builtin_amdgcn_mfma_f32_16x16x32_bf16(aw[ks], bw, d, 0, 0, 0);
            }
            mv[nf] = pack4(d);
        }
        __syncthreads();   // Tb[0] reads (phase B) done
#pragma unroll
        for (int nf = 0; nf < 4; ++nf)
            twr(Tb[0], nf * 16 + l16, wcol, mv[nf]);
    }
    __syncthreads();

    u32x4* qout = (u32x4*)(Q + (size_t)bq * PST_);
#pragma unroll
    for (int c = tid; c < 512; c += 256) {
        const int row = c >> 3;
        const int pos = c & 7;
        qout[row * 8 + pos] = trd(Tb[0], row, pos * 16);
    }
}

// ---------------------------------------------------------------------------
// scan_q: wave 0 = serial scan over quad-products (64 steps);
//         wave 1 = target-path gather (concurrent, off the critical path).
// ---------------------------------------------------------------------------
__global__ __launch_bounds__(128, 1) void scan_q(
    const __hip_bfloat16* __restrict__ Q,    // [B*Tq][PST]
    const __hip_bfloat16* __restrict__ P,    // [B*Tc][PST]
    const int* __restrict__ target, const float* __restrict__ mask,
    float* __restrict__ p_ws, float* __restrict__ ls_ws,
    float* __restrict__ tgt_ws, float* __restrict__ out,
    int t0q, int Tq, int Tqtot)
{
    __shared__ __align__(16) unsigned short p_arr[64];
    __shared__ float tgt_sh;

    const int b    = blockIdx.x;
    const int tid  = threadIdx.x;
    const int wv   = tid >> 6;
    const int lane = tid & 63;
    const int quad = lane >> 4;
    const int l16  = lane & 15;
    const int t0 = t0q << 2, Tc = Tq << 2;

    float pv[4] = {0.f, 0.f, 0.f, 0.f};
    float logscale = 0.f;

    if (wv == 0) {
        if (t0q == 0) {
            p_arr[lane] = (lane == L_ - 1) ? (unsigned short)0x3F80 : (unsigned short)0;
        } else {
#pragma unroll
            for (int f = 0; f < 4; ++f) pv[f] = p_ws[b * 64 + f * 16 + l16];
            logscale = ls_ws[b];
            p_arr[quad * 16 + l16] = bf16bits(pv[quad]);
        }
        asm volatile("s_waitcnt lgkmcnt(0)" ::: "memory");

        int off[8];
#pragma unroll
        for (int f = 0; f < 4; ++f)
#pragma unroll
            for (int ks = 0; ks < 2; ++ks)
                off[f * 2 + ks] = (f * 16 + l16) * 8 + ks * 4 + quad;

        const u32x4* gp = (const u32x4*)Q + (size_t)b * Tq * (PST_ / 8);
        const u32x4_a* pa = (const u32x4_a*)p_arr;

        u32x4 s0[8], s1[8], s2[8], s3[8];
        auto fetch = [&](u32x4 (&st)[8], int tl) {
            const u32x4* g = gp + (size_t)tl * (PST_ / 8);
#pragma unroll
            for (int q = 0; q < 8; ++q) st[q] = g[off[q]];
        };
        fetch(s0, 0);
        if (1 < Tq) fetch(s1, 1);
        if (2 < Tq) fetch(s2, 2);
        if (3 < Tq) fetch(s3, 3);

        auto step = [&](u32x4 (&st)[8], int tl) {
            bf16x8 a0 = as_bf16x8(pa[quad]);
            bf16x8 a1 = as_bf16x8(pa[4 + quad]);
            const f32x4 z = {};
            f32x4 ae[4], ao[4];
#pragma unroll
            for (int f = 0; f < 4; ++f) {
                ae[f] = __builtin_amdgcn_mfma_f32_16x16x32_bf16(a0, as_bf16x8(st[f * 2 + 0]), z, 0, 0, 0);
                ao[f] = __builtin_amdgcn_mfma_f32_16x16x32_bf16(a1, as_bf16x8(st[f * 2 + 1]), z, 0, 0, 0);
            }
#pragma unroll
            for (int f = 0; f < 4; ++f) pv[f] = ae[f][0] + ao[f][0];

            if (((tl & 1) == 1) || (tl == Tq - 1)) {
                float mx = fmaxf(fmaxf(pv[0], pv[1]), fmaxf(pv[2], pv[3]));
                DPP_STEP(mx, fmaxf, 0xB1);
                DPP_STEP(mx, fmaxf, 0x4E);
                DPP_STEP(mx, fmaxf, 0x124);
                DPP_STEP(mx, fmaxf, 0x128);
                const float inv = 1.f / mx;
                logscale += __logf(mx);
#pragma unroll
                for (int f = 0; f < 4; ++f) pv[f] *= inv;
            }
            p_arr[quad * 16 + l16] = bf16bits(pv[quad]);
            asm volatile("s_waitcnt lgkmcnt(0)" ::: "memory");
        };

        for (int tl = 0; tl < Tq; tl += 4) {
            step(s0, tl);
            if (tl + 4 < Tq) fetch(s0, tl + 4);
            if (tl + 1 < Tq) { step(s1, tl + 1); if (tl + 5 < Tq) fetch(s1, tl + 5); }
            if (tl + 2 < Tq) { step(s2, tl + 2); if (tl + 6 < Tq) fetch(s2, tl + 6); }
            if (tl + 3 < Tq) { step(s3, tl + 3); if (tl + 7 < Tq) fetch(s3, tl + 7); }
        }
    } else {
        // target-path gather
        float s = 0.f;
        for (int tl = lane; tl < Tc; tl += 64) {
            const int t = t0 + tl;
            const int j = target[b * T_ + t];
            const int i = (t == 0) ? (L_ - 1) : target[b * T_ + t - 1];
            const float m = (t == 0) ? 1.f : mask[b * T_ + t];
            if (m != 0.f) {
                const float pval =
                    __bfloat162float(P[(size_t)(b * Tc + tl) * PST_ + j * RS_ + i]);
                s += __logf(pval);
            }
        }
#pragma unroll
        for (int d = 1; d < 64; d <<= 1) s += __shfl_xor(s, d);
        if (lane == 0) {
            const float tot = (t0 == 0) ? s : tgt_ws[b] + s;
            tgt_ws[b] = tot;
            tgt_sh = tot;
        }
    }
    __syncthreads();

    if (wv == 0) {
        if (t0q + Tq == Tqtot) {
            float s = pv[0] + pv[1] + pv[2] + pv[3];
            DPP_STEP(s, addf, 0xB1);
            DPP_STEP(s, addf, 0x4E);
            DPP_STEP(s, addf, 0x124);
            DPP_STEP(s, addf, 0x128);
            if (lane == 0) out[b] = logscale + __logf(s) - tgt_sh;
        } else {
            if (quad == 0) {
#pragma unroll
                for (int f = 0; f < 4; ++f) p_ws[b * 64 + f * 16 + l16] = pv[f];
            }
            if (lane == 0) ls_ws[b] = logscale;
        }
    }
}

// ---------------------------------------------------------------------------
extern "C" void kernel_launch(void* const* d_in, const int* in_sizes, int n_in,
                              void* d_out, int out_size, void* d_ws, size_t ws_size,
                              hipStream_t stream)
{
    (void)in_sizes; (void)n_in; (void)out_size;
    const float* x       = (const float*)d_in[0];
    const float* mask    = (const float*)d_in[1];
    const int*   target  = (const int*)d_in[2];
    const float* state_W = (const float*)d_in[3];
    const float* state_b = (const float*)d_in[4];
    const float* trans_W = (const float*)d_in[5];
    const float* trans_b = (const float*)d_in[6];
    float* out = (float*)d_out;

    char* ws = (char*)d_ws;
    size_t off = 0;
    auto alloc = [&](size_t bytes) -> void* {
        void* p = ws + off;
        off = (off + bytes + 255) & ~(size_t)255;
        return p;
    };

    __hip_bfloat16* Wt   = (__hip_bfloat16*)alloc((size_t)NG_ * K_ * 2);
    float*          bias = (float*)alloc((size_t)NG_ * 4);
    __hip_bfloat16* xb   = (__hip_bfloat16*)alloc((size_t)B_ * T_ * K_ * 2);
    float*          p_ws = (float*)alloc((size_t)B_ * 64 * 4);
    float*          ls   = (float*)alloc((size_t)B_ * 4);
    float*          tgte = (float*)alloc((size_t)B_ * 4);
    const size_t fixed = off;

    int Tc = 256;
    while (Tc > 4 && fixed + (size_t)Tc * B_ * PST_ * 2 * 5 / 4 + 512 > ws_size) Tc >>= 1;
    __hip_bfloat16* P = (__hip_bfloat16*)alloc((size_t)Tc * B_ * PST_ * 2);
    __hip_bfloat16* Q = (__hip_bfloat16*)alloc((size_t)(Tc / 4) * B_ * PST_ * 2);
    int TcShift = 0;
    while ((1 << TcShift) < Tc) ++TcShift;

    prep_all<<<dim3(2112), 256, 0, stream>>>(
        trans_W, trans_b, state_W, state_b, x, Wt, bias, xb, P, Tc);

    for (int t0 = 0; t0 < T_; t0 += Tc) {
        gemm_energy<<<dim3(NG_ / NT_, (B_ * Tc) / MT_), 256, 0, stream>>>(
            xb, Wt, bias, mask, P, t0, Tc, TcShift);
        prod_quad<<<dim3(B_ * (Tc / 4)), 256, 0, stream>>>(P, Q, Tc);
        scan_q<<<dim3(B_), 128, 0, stream>>>(Q, P, target, mask, p_ws, ls, tgte, out,
                                             t0 / 4, Tc / 4, T_ / 4);
    }
}